// Round 1
// baseline (193.172 us; speedup 1.0000x reference)
//
#include <hip/hip_runtime.h>
#include <hip/hip_bf16.h>
#include <stdint.h>

// out = quantize(relu(x @ w + b)), x:8192x1024 f32, w:1024x1024 f32, b:1024 f32
// Exact bf16-limb decomposition: x = xh+xm+xl (exact, <=19-bit fixedpoint),
// w = wh+wl (exact, <=14-bit). GEMM over virtual K'=5120:
//   blocks: [xh,xm,xl,xh,xm] x [wh,wh,wh,wl,wl]
// mapped onto A3 = [xh|xm|xl] (8192x3072) and Bt2 = [wh|wl]^T (1024x2048).

typedef __attribute__((ext_vector_type(8))) short short8;
typedef __attribute__((ext_vector_type(4))) float f32x4;
typedef __attribute__((ext_vector_type(4))) unsigned short us4;

__device__ __forceinline__ unsigned short f32_to_bf16_rne(float f) {
    uint32_t u = __float_as_uint(f);
    uint32_t r = u + 0x7FFFu + ((u >> 16) & 1u);
    return (unsigned short)(r >> 16);
}
__device__ __forceinline__ float bf16_to_f32(unsigned short s) {
    return __uint_as_float(((uint32_t)s) << 16);
}

// ---------------- split x into 3 exact bf16 limbs ----------------
__global__ __launch_bounds__(256) void split_x_kernel(const float* __restrict__ x,
                                                      unsigned short* __restrict__ A3) {
    int i = blockIdx.x * 256 + threadIdx.x;           // float4 index, 2097152 total
    float4 v = reinterpret_cast<const float4*>(x)[i];
    int e = i * 4;
    int row = e >> 10;
    int col = e & 1023;
    float vv[4] = {v.x, v.y, v.z, v.w};
    us4 h, m, l;
    unsigned short* hp = (unsigned short*)&h;
    unsigned short* mp = (unsigned short*)&m;
    unsigned short* lp = (unsigned short*)&l;
#pragma unroll
    for (int j = 0; j < 4; ++j) {
        float f = vv[j];
        unsigned short hb = f32_to_bf16_rne(f);
        float r1 = f - bf16_to_f32(hb);
        unsigned short mb = f32_to_bf16_rne(r1);
        float r2 = r1 - bf16_to_f32(mb);
        unsigned short lb = f32_to_bf16_rne(r2);
        hp[j] = hb; mp[j] = mb; lp[j] = lb;
    }
    size_t base = (size_t)row * 3072 + col;
    *reinterpret_cast<us4*>(&A3[base])        = h;
    *reinterpret_cast<us4*>(&A3[base + 1024]) = m;
    *reinterpret_cast<us4*>(&A3[base + 2048]) = l;
}

// ---------------- transpose + split w into 2 exact bf16 limbs ----------------
__global__ __launch_bounds__(1024) void split_w_kernel(const float* __restrict__ w,
                                                       unsigned short* __restrict__ Bt2) {
    __shared__ float ts[32][33];
    int tx = threadIdx.x, ty = threadIdx.y;
    int n0 = blockIdx.x * 32, k0 = blockIdx.y * 32;
    ts[ty][tx] = w[(size_t)(k0 + ty) * 1024 + (n0 + tx)];
    __syncthreads();
    float f = ts[tx][ty];                      // = w[k0+tx][n0+ty]
    unsigned short h = f32_to_bf16_rne(f);
    float r = f - bf16_to_f32(h);
    unsigned short l = f32_to_bf16_rne(r);
    int n = n0 + ty, k = k0 + tx;
    Bt2[(size_t)n * 2048 + k]        = h;
    Bt2[(size_t)n * 2048 + 1024 + k] = l;
}

// ---------------- GEMM: 128x128 tile, BK=64, 4 waves, mfma 16x16x32 bf16 ----------------
__device__ __forceinline__ void load16_to_lds(const void* g, void* l) {
    __builtin_amdgcn_global_load_lds(
        (const __attribute__((address_space(1))) unsigned int*)g,
        (__attribute__((address_space(3))) unsigned int*)l,
        16, 0, 0);
}

__global__ __launch_bounds__(256, 2) void gemm_kernel(const unsigned short* __restrict__ A3,
                                                      const unsigned short* __restrict__ Bt2,
                                                      const float* __restrict__ bias,
                                                      float* __restrict__ out) {
    __shared__ unsigned short As[128 * 64];   // 16 KB, rows of 128 B (8 x 16B chunks)
    __shared__ unsigned short Bs[128 * 64];   // 16 KB

    const int tid  = threadIdx.x;
    const int lane = tid & 63;
    const int wave = tid >> 6;
    const int wr = wave >> 1, wc = wave & 1;  // 2x2 waves, each 64x64 output

    const int bm = blockIdx.x >> 3;
    const int bn = blockIdx.x & 7;
    const int m0 = bm * 128, n0 = bn * 128;

    f32x4 acc[4][4];
#pragma unroll
    for (int i = 0; i < 4; ++i)
#pragma unroll
        for (int j = 0; j < 4; ++j) acc[i][j] = (f32x4)0.0f;

    // per-thread staging geometry (constant over kt): chunk c = it*256 + tid
    // LDS dest is linear (global_load_lds constraint); global source is
    // pre-swizzled (chunk ^ (row&7)) so reads can use the same XOR (rule 21).

    for (int kt = 0; kt < 80; ++kt) {
        const int blk = kt >> 4, sub = kt & 15;
        const int aoff = (blk < 3 ? blk : blk - 3) * 1024 + sub * 64; // A3 col base
        const int boff = (blk < 3 ? 0 : 1024) + sub * 64;             // Bt2 col base

        __syncthreads();   // prior compute done before overwriting LDS
#pragma unroll
        for (int it = 0; it < 4; ++it) {
            int c = it * 256 + tid;          // 0..1023 (16B chunks)
            int row = c >> 3;
            int chg = (c & 7) ^ (row & 7);   // swizzled source chunk
            const unsigned short* ga = A3  + (size_t)(m0 + row) * 3072 + aoff + chg * 8;
            const unsigned short* gb = Bt2 + (size_t)(n0 + row) * 2048 + boff + chg * 8;
            load16_to_lds(ga, (char*)As + c * 16);
            load16_to_lds(gb, (char*)Bs + c * 16);
        }
        __syncthreads();   // compiler drains vmcnt(0) before barrier -> data ready

#pragma unroll
        for (int kk = 0; kk < 2; ++kk) {
            const int ch = kk * 4 + (lane >> 4);   // logical 16B chunk (k-slot)
            short8 af[4], bf[4];
#pragma unroll
            for (int f = 0; f < 4; ++f) {
                int ar = wr * 64 + f * 16 + (lane & 15);
                af[f] = *reinterpret_cast<const short8*>(
                            (const char*)As + ar * 128 + (ch ^ (ar & 7)) * 16);
                int br = wc * 64 + f * 16 + (lane & 15);
                bf[f] = *reinterpret_cast<const short8*>(
                            (const char*)Bs + br * 128 + (ch ^ (br & 7)) * 16);
            }
#pragma unroll
            for (int i = 0; i < 4; ++i)
#pragma unroll
                for (int j = 0; j < 4; ++j)
                    acc[i][j] = __builtin_amdgcn_mfma_f32_16x16x32_bf16(af[i], bf[j],
                                                                        acc[i][j], 0, 0, 0);
        }
    }

    // epilogue: bias + relu + quantize (RNE matches jnp.round)
    const int colBase = n0 + wc * 64 + (lane & 15);
    const int rowBase = m0 + wr * 64 + ((lane >> 4) << 2);
#pragma unroll
    for (int i = 0; i < 4; ++i) {
#pragma unroll
        for (int j = 0; j < 4; ++j) {
            int col = colBase + j * 16;
            float bv = bias[col];
#pragma unroll
            for (int r = 0; r < 4; ++r) {
                int row = rowBase + i * 16 + r;
                float y = acc[i][j][r] + bv;
                y = fmaxf(y, 0.0f);
                y = rintf(y * 65536.0f) * (1.0f / 65536.0f);
                out[(size_t)row * 1024 + col] = y;
            }
        }
    }
}

// ---------------- fallback (ws too small): naive fp32 ----------------
__global__ __launch_bounds__(256) void naive_kernel(const float* __restrict__ x,
                                                    const float* __restrict__ w,
                                                    const float* __restrict__ bias,
                                                    float* __restrict__ out) {
    int idx = blockIdx.x * 256 + threadIdx.x;
    int row = idx >> 10, col = idx & 1023;
    float s = bias[col];
    for (int k = 0; k < 1024; ++k)
        s += x[(size_t)row * 1024 + k] * w[(size_t)k * 1024 + col];
    s = fmaxf(s, 0.0f);
    out[idx] = rintf(s * 65536.0f) * (1.0f / 65536.0f);
}

extern "C" void kernel_launch(void* const* d_in, const int* in_sizes, int n_in,
                              void* d_out, int out_size, void* d_ws, size_t ws_size,
                              hipStream_t stream) {
    const float* x = (const float*)d_in[0];
    const float* w = (const float*)d_in[1];
    const float* b = (const float*)d_in[2];
    float* out = (float*)d_out;

    const size_t needA = (size_t)8192 * 3072 * 2;   // 48 MB
    const size_t needB = (size_t)1024 * 2048 * 2;   //  4 MB
    if (ws_size < needA + needB) {
        naive_kernel<<<(8192 * 1024) / 256, 256, 0, stream>>>(x, w, b, out);
        return;
    }
    unsigned short* A3  = (unsigned short*)d_ws;
    unsigned short* Bt2 = (unsigned short*)((char*)d_ws + needA);

    split_x_kernel<<<(8192 * 1024 / 4) / 256, 256, 0, stream>>>(x, A3);
    split_w_kernel<<<dim3(32, 32), dim3(32, 32), 0, stream>>>(w, Bt2);
    gemm_kernel<<<512, 256, 0, stream>>>(A3, Bt2, b, out);
}

// Round 2
// 146.794 us; speedup vs baseline: 1.3159x; 1.3159x over previous
//
#include <hip/hip_runtime.h>
#include <hip/hip_bf16.h>
#include <stdint.h>

// out = quantize(relu(x @ w + b)), x:8192x1024 f32 (fixed-point 2^-16 grid),
// w:1024x1024 f32 (grid), b:1024 zeros.
// 3-limb-product bf16 decomposition: x = xh+xm (+xl dropped), w = wh+wl.
//   y ~= xh*wh + xm*wh + xh*wl   (dropped xl*wh ~3e-5 rms, xm*wl ~5e-6 rms)
// Virtual K' = 3*1024 = 3072 over A2 = [xh|xm] (8192x2048) and
// Bt2 = [wh|wl]^T (1024x2048).
// GEMM: 256x128 tile, BK=64, 8 waves (4Mx2N, 64x64 each), double-buffered
// LDS with 2-phase pipeline (stage t+1 before compute t, one barrier/tile),
// XOR bank swizzle (rule 21: linear LDS dest + pre-swizzled global source),
// bijective XCD swizzle (each XCD owns 4 bm-panels -> A L2-resident).

typedef __attribute__((ext_vector_type(8))) short short8;
typedef __attribute__((ext_vector_type(4))) float f32x4;
typedef __attribute__((ext_vector_type(4))) unsigned short us4;

__device__ __forceinline__ unsigned short f32_to_bf16_rne(float f) {
    uint32_t u = __float_as_uint(f);
    uint32_t r = u + 0x7FFFu + ((u >> 16) & 1u);
    return (unsigned short)(r >> 16);
}
__device__ __forceinline__ float bf16_to_f32(unsigned short s) {
    return __uint_as_float(((uint32_t)s) << 16);
}

// ---------------- split x into 2 exact bf16 limbs (h, m) ----------------
__global__ __launch_bounds__(256) void split_x_kernel(const float* __restrict__ x,
                                                      unsigned short* __restrict__ A2) {
    int i = blockIdx.x * 256 + threadIdx.x;           // float4 index, 2097152 total
    float4 v = reinterpret_cast<const float4*>(x)[i];
    int e = i * 4;
    int row = e >> 10;
    int col = e & 1023;
    float vv[4] = {v.x, v.y, v.z, v.w};
    us4 h, m;
    unsigned short* hp = (unsigned short*)&h;
    unsigned short* mp = (unsigned short*)&m;
#pragma unroll
    for (int j = 0; j < 4; ++j) {
        float f = vv[j];
        unsigned short hb = f32_to_bf16_rne(f);
        float r1 = f - bf16_to_f32(hb);
        unsigned short mb = f32_to_bf16_rne(r1);
        hp[j] = hb; mp[j] = mb;
    }
    size_t base = (size_t)row * 2048 + col;
    *reinterpret_cast<us4*>(&A2[base])        = h;
    *reinterpret_cast<us4*>(&A2[base + 1024]) = m;
}

// ---------------- transpose + split w into 2 exact bf16 limbs ----------------
__global__ __launch_bounds__(1024) void split_w_kernel(const float* __restrict__ w,
                                                       unsigned short* __restrict__ Bt2) {
    __shared__ float ts[32][33];
    int tx = threadIdx.x, ty = threadIdx.y;
    int n0 = blockIdx.x * 32, k0 = blockIdx.y * 32;
    ts[ty][tx] = w[(size_t)(k0 + ty) * 1024 + (n0 + tx)];
    __syncthreads();
    float f = ts[tx][ty];                      // = w[k0+tx][n0+ty]
    unsigned short h = f32_to_bf16_rne(f);
    float r = f - bf16_to_f32(h);
    unsigned short l = f32_to_bf16_rne(r);
    int n = n0 + ty, k = k0 + tx;
    Bt2[(size_t)n * 2048 + k]        = h;
    Bt2[(size_t)n * 2048 + 1024 + k] = l;
}

// ---------------- GEMM ----------------
#define BM 256
#define BN 128
#define BK 64
#define NT 48   // 3 limb-product blocks x 16 sub-tiles of 64

__device__ __forceinline__ void load16_to_lds(const void* g, void* l) {
    __builtin_amdgcn_global_load_lds(
        (const __attribute__((address_space(1))) unsigned int*)g,
        (__attribute__((address_space(3))) unsigned int*)l,
        16, 0, 0);
}

__global__ __launch_bounds__(512, 2) void gemm_kernel(const unsigned short* __restrict__ A2,
                                                      const unsigned short* __restrict__ Bt2,
                                                      const float* __restrict__ bias,
                                                      float* __restrict__ out) {
    __shared__ unsigned short As[2][BM * BK];   // 2 x 32 KB
    __shared__ unsigned short Bs[2][BN * BK];   // 2 x 16 KB

    const int tid  = threadIdx.x;
    const int lane = tid & 63;
    const int wave = tid >> 6;
    const int wr = wave >> 1, wc = wave & 1;    // 4M x 2N waves, each 64x64 out

    // Bijective XCD swizzle: grid=256, xcd = bid%8 gets bm in {4*xcd..4*xcd+3},
    // all 8 bn -> A-panel reused 8x within one XCD's L2.
    const int bid = blockIdx.x;
    const int wg  = (bid & 7) * 32 + (bid >> 3);
    const int bm = wg >> 3, bn = wg & 7;
    const int m0 = bm * BM, n0 = bn * BN;

    f32x4 acc[4][4];
#pragma unroll
    for (int i = 0; i < 4; ++i)
#pragma unroll
        for (int j = 0; j < 4; ++j) acc[i][j] = (f32x4)0.0f;

    // virtual-K block tables: A segments [h, m, h], B segments [wh, wh, wl]
    const int Aseg[3] = {0, 1024, 0};
    const int Bseg[3] = {0, 0, 1024};

    auto stage = [&](int b, int t) {
        const int blk = t >> 4, sub = t & 15;
        const int aoff = Aseg[blk] + sub * 64;
        const int boff = Bseg[blk] + sub * 64;
#pragma unroll
        for (int it = 0; it < 4; ++it) {        // A: 2048 16B chunks / 512 thr
            int c = it * 512 + tid;
            int row = c >> 3;
            int sw = (c & 7) ^ (row & 7);       // pre-swizzled global source
            load16_to_lds(A2 + (size_t)(m0 + row) * 2048 + aoff + sw * 8,
                          (char*)As[b] + c * 16);
        }
#pragma unroll
        for (int it = 0; it < 2; ++it) {        // B: 1024 chunks / 512 thr
            int c = it * 512 + tid;
            int row = c >> 3;
            int sw = (c & 7) ^ (row & 7);
            load16_to_lds(Bt2 + (size_t)(n0 + row) * 2048 + boff + sw * 8,
                          (char*)Bs[b] + c * 16);
        }
    };

    auto compute = [&](int b) {
#pragma unroll
        for (int kk = 0; kk < 2; ++kk) {
            const int ch = kk * 4 + (lane >> 4);     // logical k-chunk 0..7
            short8 af[4], bf[4];
#pragma unroll
            for (int f = 0; f < 4; ++f) {
                int ar = wr * 64 + f * 16 + (lane & 15);
                af[f] = *reinterpret_cast<const short8*>(
                            (const char*)As[b] + ar * 128 + ((ch ^ (ar & 7)) * 16));
                int br = wc * 64 + f * 16 + (lane & 15);
                bf[f] = *reinterpret_cast<const short8*>(
                            (const char*)Bs[b] + br * 128 + ((ch ^ (br & 7)) * 16));
            }
#pragma unroll
            for (int i = 0; i < 4; ++i)
#pragma unroll
                for (int j = 0; j < 4; ++j)
                    acc[i][j] = __builtin_amdgcn_mfma_f32_16x16x32_bf16(af[i], bf[j],
                                                                        acc[i][j], 0, 0, 0);
        }
    };

    // 2-phase pipeline: stage(t+1) issued before compute(t); the barrier's
    // implicit vmcnt(0) drain is covered by a full tile of compute.
    stage(0, 0);
    __syncthreads();
    for (int t = 0; t < NT; t += 2) {
        if (t + 1 < NT) stage(1, t + 1);
        compute(0);
        __syncthreads();
        if (t + 2 < NT) stage(0, t + 2);
        compute(1);
        __syncthreads();
    }

    // epilogue: bias + relu + quantize (RNE matches jnp.round)
    const int colBase = n0 + wc * 64 + (lane & 15);
    const int rowBase = m0 + wr * 64 + ((lane >> 4) << 2);
#pragma unroll
    for (int i = 0; i < 4; ++i) {
#pragma unroll
        for (int j = 0; j < 4; ++j) {
            int col = colBase + j * 16;
            float bv = bias[col];
#pragma unroll
            for (int r = 0; r < 4; ++r) {
                int row = rowBase + i * 16 + r;
                float y = acc[i][j][r] + bv;
                y = fmaxf(y, 0.0f);
                y = rintf(y * 65536.0f) * (1.0f / 65536.0f);
                out[(size_t)row * 1024 + col] = y;
            }
        }
    }
}

// ---------------- fallback (ws too small): naive fp32 ----------------
__global__ __launch_bounds__(256) void naive_kernel(const float* __restrict__ x,
                                                    const float* __restrict__ w,
                                                    const float* __restrict__ bias,
                                                    float* __restrict__ out) {
    int idx = blockIdx.x * 256 + threadIdx.x;
    int row = idx >> 10, col = idx & 1023;
    float s = bias[col];
    for (int k = 0; k < 1024; ++k)
        s += x[(size_t)row * 1024 + k] * w[(size_t)k * 1024 + col];
    s = fmaxf(s, 0.0f);
    out[idx] = rintf(s * 65536.0f) * (1.0f / 65536.0f);
}

extern "C" void kernel_launch(void* const* d_in, const int* in_sizes, int n_in,
                              void* d_out, int out_size, void* d_ws, size_t ws_size,
                              hipStream_t stream) {
    const float* x = (const float*)d_in[0];
    const float* w = (const float*)d_in[1];
    const float* b = (const float*)d_in[2];
    float* out = (float*)d_out;

    const size_t needA = (size_t)8192 * 2048 * 2;   // 32 MB
    const size_t needB = (size_t)1024 * 2048 * 2;   //  4 MB
    if (ws_size < needA + needB) {
        naive_kernel<<<(8192 * 1024) / 256, 256, 0, stream>>>(x, w, b, out);
        return;
    }
    unsigned short* A2  = (unsigned short*)d_ws;
    unsigned short* Bt2 = (unsigned short*)((char*)d_ws + needA);

    split_x_kernel<<<(8192 * 1024 / 4) / 256, 256, 0, stream>>>(x, A2);
    split_w_kernel<<<dim3(32, 32), dim3(32, 32), 0, stream>>>(w, Bt2);
    gemm_kernel<<<256, 512, 0, stream>>>(A2, Bt2, b, out);
}